// Round 6
// baseline (879.872 us; speedup 1.0000x reference)
//
#include <hip/hip_runtime.h>

// ---------------------------------------------------------------------------
// AggregationGNN: edge embed (cat tables + RBF) -> gather src -> scatter-add
// at dst -> per-node 2-layer MLP (64->128->64, relu both).
//
//  * Edge kernel: wave per edge-chunk (grid-stride chunked, ~61 edges/wave);
//    lane = feature f. Per-lane RBF weights (Bk[k]*rbfW[k][d]) + rbf_b
//    hoisted into registers once per wave. Half-wave split: lanes f<32
//    compute r-side, f>=32 p-side; r-part crosses via shfl_xor(32)
//    (rbf_b cancels in p-r).   [R5: edge ~418us, memory/atomic-wall bound]
//  * RBF: exp(-10(L-0.1k)^2) = A * T^k * Bk, A=exp(-10L^2), T=exp(2L),
//    Bk=exp(-0.1k^2) folded into hoisted weights; A folded into the seed.
//  * Aggregation: f32 atomicAdd into d_out (device-scope), 256B/wave.
//  * MLP: in-place on d_out; one thread per node; a[64]+acc[64] in VGPRs.
//    __launch_bounds__(256, 2): R5 showed VGPR_Count=72 with 128+ live
//    floats -> scratch spill (WRITE_SIZE 537MB vs 128MB output). The 2nd
//    arg (min waves/EU=2) raises the VGPR cap to 256 so acc/a stay in regs.
//    Weight rows uniformly addressed (uniform j + SGPR base) -> s_load.
// ---------------------------------------------------------------------------

#define CD 64
#define HID 128

__global__ __launch_bounds__(256) void transpose_w1_kernel(
    const float* __restrict__ W1,   // [64][128]
    float* __restrict__ W1t)        // [128][64]
{
    int idx = blockIdx.x * 256 + threadIdx.x;   // 8192 total
    if (idx >= 64 * 128) return;
    int i = idx >> 7;        // 0..63
    int j = idx & 127;       // 0..127
    W1t[j * 64 + i] = W1[i * 128 + j];
}

__global__ __launch_bounds__(256) void edge_kernel(
    const float* __restrict__ atom,     // [N][64]
    const int*   __restrict__ srcv, const int* __restrict__ dstv,
    const int*   __restrict__ rdv,  const int* __restrict__ rtv, const int* __restrict__ rrv,
    const int*   __restrict__ pdv,  const int* __restrict__ ptv, const int* __restrict__ prv,
    const float* __restrict__ rlenv, const float* __restrict__ plenv,
    const float* __restrict__ Edir,  // [8][32]
    const float* __restrict__ Etyp,  // [16][32]
    const float* __restrict__ Erng,  // [4][32]
    const float* __restrict__ rbfW,  // [20][32]
    const float* __restrict__ rbfB,  // [32]
    float* __restrict__ agg,         // [N][64], pre-zeroed
    int nE)
{
    int wid = __builtin_amdgcn_readfirstlane(blockIdx.x * 4 + (threadIdx.x >> 6));
    int nw  = gridDim.x * 4;         // waves in grid
    int f   = threadIdx.x & 63;      // output feature 0..63
    int d   = f & 31;                // embed dim 0..31
    bool rhalf = (f < 32);

    const float Bk[20] = {
        1.0f,            9.0483742e-1f,  6.7032005e-1f,  4.0656966e-1f,
        2.0189652e-1f,   8.2084999e-2f,  2.7323722e-2f,  7.4465830e-3f,
        1.6615573e-3f,   3.0353914e-4f,  4.5399930e-5f,  5.5595310e-6f,
        5.5739037e-7f,   4.5753326e-8f,  3.0748799e-9f,  1.6918798e-10f,
        7.6217622e-12f,  2.8111856e-13f, 8.4885308e-15f, 2.0984571e-16f
    };

    // hoisted per-lane RBF weights (even/odd k pairs) + bias — reused ~61x
    float wkx[10], wky[10];
#pragma unroll
    for (int m = 0; m < 10; ++m) {
        wkx[m] = Bk[2 * m]     * rbfW[(2 * m) * 32 + d];
        wky[m] = Bk[2 * m + 1] * rbfW[(2 * m + 1) * 32 + d];
    }
    float bias = rbfB[d];

    int per = (nE + nw - 1) / nw;    // contiguous chunk per wave
    int beg = wid * per;
    int end = beg + per; if (end > nE) end = nE;

    for (int e = beg; e < end; ++e) {
        int   s  = srcv[e];
        int   t  = dstv[e];
        int   id = rhalf ? rdv[e]   : pdv[e];
        int   it = rhalf ? rtv[e]   : ptv[e];
        int   ir = rhalf ? rrv[e]   : prv[e];
        float L  = rhalf ? rlenv[e] : plenv[e];

        float cat = Edir[id * 32 + d] + Etyp[it * 32 + d] + Erng[ir * 32 + d];

        float A  = __expf(-10.f * L * L);
        float T  = __expf(2.f * L);
        float T2 = T * T;
        float px = A, py = A * T;     // A folded into the recurrence seed
        float ax = 0.f, ay = 0.f;
#pragma unroll
        for (int m = 0; m < 10; ++m) {
            ax = fmaf(px, wkx[m], ax);
            ay = fmaf(py, wky[m], ay);
            px *= T2;
            py *= T2;
        }
        float mine = cat + ax + ay;           // my half's cat + rbf@W (no bias)

        float other = __shfl_xor(mine, 32);   // lower half's value to upper
        float val = rhalf ? (mine + bias)     // r_embed
                          : (mine - other);   // p_embed - r_embed (bias cancels)

        float msg = atom[(size_t)s * CD + f] + val;
        atomicAdd(&agg[(size_t)t * CD + f], msg);
    }
}

__global__ __launch_bounds__(256, 2) void mlp_kernel(
    const float* __restrict__ W1t,  // [128][64] transposed
    const float* __restrict__ b1,   // [128]
    const float* __restrict__ W2,   // [128][64]
    const float* __restrict__ b2,   // [64]
    float* __restrict__ io,         // [N][64]: in = agg, out = result (in-place)
    int nN)
{
    int n = blockIdx.x * 256 + threadIdx.x;
    if (n >= nN) return;
    float* row = io + (size_t)n * CD;

    float a[CD];
#pragma unroll
    for (int i = 0; i < CD / 4; ++i) {
        float4 v = reinterpret_cast<const float4*>(row)[i];
        a[4 * i + 0] = v.x; a[4 * i + 1] = v.y;
        a[4 * i + 2] = v.z; a[4 * i + 3] = v.w;
    }

    float acc[CD];
#pragma unroll
    for (int o = 0; o < CD; ++o) acc[o] = b2[o];

#pragma unroll 2
    for (int j = 0; j < HID; ++j) {
        const float* w1 = W1t + (size_t)j * CD;   // uniform address -> s_load
        float h0 = b1[j], h1 = 0.f, h2 = 0.f, h3 = 0.f;
#pragma unroll
        for (int i = 0; i < CD / 4; ++i) {
            h0 = fmaf(a[4 * i + 0], w1[4 * i + 0], h0);
            h1 = fmaf(a[4 * i + 1], w1[4 * i + 1], h1);
            h2 = fmaf(a[4 * i + 2], w1[4 * i + 2], h2);
            h3 = fmaf(a[4 * i + 3], w1[4 * i + 3], h3);
        }
        float h = fmaxf((h0 + h1) + (h2 + h3), 0.f);

        const float* w2 = W2 + (size_t)j * CD;    // uniform address -> s_load
#pragma unroll
        for (int o = 0; o < CD; ++o) acc[o] = fmaf(h, w2[o], acc[o]);
    }

#pragma unroll
    for (int i = 0; i < CD / 4; ++i) {
        float4 v;
        v.x = fmaxf(acc[4 * i + 0], 0.f);
        v.y = fmaxf(acc[4 * i + 1], 0.f);
        v.z = fmaxf(acc[4 * i + 2], 0.f);
        v.w = fmaxf(acc[4 * i + 3], 0.f);
        reinterpret_cast<float4*>(row)[i] = v;
    }
}

extern "C" void kernel_launch(void* const* d_in, const int* in_sizes, int n_in,
                              void* d_out, int out_size, void* d_ws, size_t ws_size,
                              hipStream_t stream) {
    const float* atom  = (const float*)d_in[0];
    const int*   srcv  = (const int*)d_in[1];
    const int*   dstv  = (const int*)d_in[2];
    const int*   rdv   = (const int*)d_in[3];
    const int*   rtv   = (const int*)d_in[4];
    const int*   rrv   = (const int*)d_in[5];
    const int*   pdv   = (const int*)d_in[6];
    const int*   ptv   = (const int*)d_in[7];
    const int*   prv   = (const int*)d_in[8];
    const float* rlenv = (const float*)d_in[9];
    const float* plenv = (const float*)d_in[10];
    const float* Edir  = (const float*)d_in[11];
    const float* Etyp  = (const float*)d_in[12];
    const float* Erng  = (const float*)d_in[13];
    const float* rbfW  = (const float*)d_in[14];
    const float* rbfB  = (const float*)d_in[15];
    const float* W1    = (const float*)d_in[16];
    const float* b1    = (const float*)d_in[17];
    const float* W2    = (const float*)d_in[18];
    const float* b2    = (const float*)d_in[19];

    int nE = in_sizes[1];           // 1,000,000
    int nN = in_sizes[0] / CD;      // 500,000

    float* agg = (float*)d_out;     // aggregate directly into output buffer
    float* W1t = (float*)d_ws;      // 32 KB scratch for transposed W1

    // zero the aggregation buffer (harness poisons d_out each replay)
    (void)hipMemsetAsync(agg, 0, (size_t)nN * CD * sizeof(float), stream);

    transpose_w1_kernel<<<32, 256, 0, stream>>>(W1, W1t);

    // 4096 blocks x 4 waves = 16384 waves; ~61 contiguous edges per wave
    // (R6 probe: if edge time is unchanged vs 2048 blocks, latency-hiding is
    //  not the limiter -> random-RMW wall confirmed -> CSR pull model next)
    edge_kernel<<<4096, 256, 0, stream>>>(
        atom, srcv, dstv, rdv, rtv, rrv, pdv, ptv, prv, rlenv, plenv,
        Edir, Etyp, Erng, rbfW, rbfB, agg, nE);

    mlp_kernel<<<(nN + 255) / 256, 256, 0, stream>>>(W1t, b1, W2, b2, agg, nN);
}